// Round 1
// 92.724 us; speedup vs baseline: 1.0170x; 1.0170x over previous
//
#include <hip/hip_runtime.h>
#include <math.h>

#define NB     64
#define NPTS   8192
#define S2D    384
#define GW     128
#define QROWS  32                 // rows of the 128-row grid per B-block
#define BLK    1024
#define ACCN   (QROWS * GW * 3)   // 12288 floats = 48 KB

// Workspace layout (u32 units):
//   [0 .. NB*8)           per-(batch,part) offset-min partials: [b][part][ch]
//   [1024 .. 1024+NB*NPTS) packed keys: (u0+512) | (u1+512)<<16, u = gi/3
#define WS_KEYS_OFF 1024

// ---------------------------------------------------------------------------
// Kernel A: exact lattice pipeline, ONCE per point. 256 blocks = 64 b x 4 part,
// 2048 points per block (2 per thread). XCD-swizzled so all 4 parts of a batch
// land on one XCD (keys stay hot in that XCD's L2 for kernel B).
// ---------------------------------------------------------------------------
__global__ __launch_bounds__(1024) void lattice_keys(const float* __restrict__ pc1,
                                                     const float* __restrict__ tm,
                                                     unsigned int* __restrict__ ws) {
    const int x    = blockIdx.x;
    const int xcd  = x & 7;
    const int slot = x >> 3;              // 0..31
    const int b    = xcd * 8 + (slot >> 2);
    const int part = slot & 3;
    const int tid  = threadIdx.x;

    __shared__ int s_min[2];
    if (tid < 2) s_min[tid] = 0x7FFFFFFF;
    __syncthreads();

    float t[9];
#pragma unroll
    for (int i = 0; i < 9; i++) t[i] = tm[b * 9 + i];

    int m0 = 0x7FFFFFFF, m1 = 0x7FFFFFFF;

#pragma unroll
    for (int k = 0; k < 2; k++) {
        const int n = part * 2048 + tid + k * BLK;
        const float p0 = pc1[((size_t)b * 3 + 0) * NPTS + n];
        const float p1 = pc1[((size_t)b * 3 + 1) * NPTS + n];
        const float p2 = pc1[((size_t)b * 3 + 2) * NPTS + n];

        float v[3];
        int   ur[3];
#pragma unroll
        for (int i = 0; i < 3; i++) {
            // fma-ascending 3-term dot, correctly-rounded /3, round-half-even
            float e  = fmaf(t[i*3+2], p2, fmaf(t[i*3+1], p1, t[i*3+0] * p0));
            float qq = __fdiv_rn(e, 3.0f);
            float rq = rintf(qq);          // g = rq*3 exact in fp32
            ur[i] = (int)rq;               // u' = g/3
            v[i]  = e - rq * 3.0f;         // exact (Sterbenz)
        }

        // remainder_sum: sum(g)/3 is exact integer arithmetic -> do it in int.
        const int rs = ur[0] + ur[1] + ur[2];

        unsigned int key = 0;
#pragma unroll
        for (int i = 0; i < 2; i++) {      // only lattice channels 0,1 matter
            int r = 0;
#pragma unroll
            for (int j = 0; j < 3; j++)
                if (v[j] > v[i] || (v[j] == v[i] && j < i)) r++;
            // cond on exact small ints == the verified float comparisons
            const bool cond = ((r >= 3 - rs) && (rs > 0)) ||
                              ((r <  -rs)   && (rs < 0));
            const int s    = cond ? (rs > 0 ? -1 : 1) : 0;   // shift/3
            const int u    = ur[i] + s;                      // gi/3
            const int rfin = r + 3 * s + rs;
            const int cl   = min(max(rfin, 0), 2);           // CANONICAL row-min = -cl
            const int cand = 3 * u - cl;
            if (i == 0) { m0 = min(m0, cand); key |= (unsigned)(u + 512); }
            else        { m1 = min(m1, cand); key |= ((unsigned)(u + 512)) << 16; }
        }
        ws[WS_KEYS_OFF + (size_t)b * NPTS + n] = key;
    }

    // wave64 min-reduction, then cross-wave via LDS atomicMin
#pragma unroll
    for (int off = 32; off > 0; off >>= 1) {
        m0 = min(m0, __shfl_down(m0, off));
        m1 = min(m1, __shfl_down(m1, off));
    }
    if ((tid & 63) == 0) {
        atomicMin(&s_min[0], m0);
        atomicMin(&s_min[1], m1);
    }
    __syncthreads();
    if (tid == 0) {
        ws[b * 8 + part * 2 + 0] = (unsigned int)s_min[0];
        ws[b * 8 + part * 2 + 1] = (unsigned int)s_min[1];
    }
}

// ---------------------------------------------------------------------------
// Kernel B: scatter + writeout. 256 blocks = 64 b x 4 quarters, XCD-swizzled
// identically to A so keys (32 KB/batch) + feat (96 KB/batch) are L2-resident
// on the owning XCD across the 4 quarter-blocks.
// ---------------------------------------------------------------------------
__global__ __launch_bounds__(1024) void splat_out(const float* __restrict__ feat,
                                                  const unsigned int* __restrict__ ws,
                                                  float* __restrict__ out) {
    const int x    = blockIdx.x;
    const int xcd  = x & 7;
    const int slot = x >> 3;
    const int b    = xcd * 8 + (slot >> 2);
    const int q    = slot & 3;
    const int tid  = threadIdx.x;

    __shared__ __align__(16) float acc[ACCN];
    __shared__ int s_part[8];

    if (tid < 8) s_part[tid] = ((const int*)ws)[b * 8 + tid];
#pragma unroll
    for (int i = 0; i < ACCN / BLK; i++)
        acc[tid + i * BLK] = 0.0f;
    __syncthreads();

    const int off0 = min(min(s_part[0], s_part[2]), min(s_part[4], s_part[6]));
    const int off1 = min(min(s_part[1], s_part[3]), min(s_part[5], s_part[7]));
    const int pp0  = ((-off0) % 3 + 3) % 3;
    const int pp1  = ((-off1) % 3 + 3) % 3;
    const int U0   = (off0 + pp0) / 3;    // off0+pp0 is a multiple of 3 -> exact
    const int U1   = (off1 + pp1) / 3;
    const int rlo  = q * QROWS;

    const unsigned int* __restrict__ keys = ws + WS_KEYS_OFF + (size_t)b * NPTS;
    const float* __restrict__ fb = feat + (size_t)b * 3 * NPTS;

#pragma unroll
    for (int k = 0; k < NPTS / BLK; k++) {      // 8 keys per thread
        const int n = tid + k * BLK;
        const unsigned int key = keys[n];
        // i0 = u0 - U0 == (c0 - pp0)/3 of the verified kernel; same for j0.
        const int i0 = (int)(key & 0xFFFFu) - 512 - U0;
        const int j0 = (int)(key >> 16)     - 512 - U1;
        const unsigned int ri = (unsigned int)(i0 - rlo);
        if (ri < QROWS && (unsigned int)j0 < GW) {
            float* dst = acc + (ri * GW + (unsigned int)j0) * 3;
            atomicAdd(dst + 0, fb[n]);
            atomicAdd(dst + 1, fb[NPTS + n]);
            atomicAdd(dst + 2, fb[2 * NPTS + n]);
        }
    }
    __syncthreads();

    // coalesced float4 writeout (fully overwrites -> no memset needed)
    float4* __restrict__ dst4 = (float4*)(out + ((size_t)b * GW + rlo) * GW * 3);
    const float4* __restrict__ src4 = (const float4*)acc;
#pragma unroll
    for (int i = 0; i < ACCN / (4 * BLK); i++)   // 3 float4 per thread
        dst4[tid + i * BLK] = src4[tid + i * BLK];
}

extern "C" void kernel_launch(void* const* d_in, const int* in_sizes, int n_in,
                              void* d_out, int out_size, void* d_ws, size_t ws_size,
                              hipStream_t stream) {
    const float* pc1  = (const float*)d_in[0];   // [64,3,8192]
    const float* feat = (const float*)d_in[1];   // [64,3,8192]
    const float* tm   = (const float*)d_in[2];   // [64,3,3]
    float* out = (float*)d_out;                  // [64,128,128,3]
    unsigned int* ws  = (unsigned int*)d_ws;     // needs 4 KB + 2 MB

    lattice_keys<<<NB * 4, BLK, 0, stream>>>(pc1, tm, ws);
    splat_out<<<NB * 4, BLK, 0, stream>>>(feat, ws, out);
}